// Round 5
// baseline (671.247 us; speedup 1.0000x reference)
//
#include <hip/hip_runtime.h>
#include <math.h>

#define Bn 16
#define An 65472
#define Cn 81
#define Gn 50
#define ROWS 64        // rows per chunk
#define NCH 8          // chunks per k2 block (512 rows/block)
#define BROWS (ROWS * NCH)
#define CHUNK_F4 1296  // float4s per chunk = ROWS*Cn/4
#define LD_T 216       // threads issuing DMA loads (216*6 = 1296)
#define LD_K 6         // DMA loads per issuing thread -> uniform 6 VMEM per wave
#define NBUCK 1024
#define LISTCAP 8192

static_assert((Bn * (long long)An) % BROWS == 0, "grid covers rows exactly");
static_assert(LD_T * LD_K == CHUNK_F4, "uniform load split");

constexpr float POS_THRESH_C = 0.5f;
constexpr float BETA_C = 1.0f / 9.0f;

typedef const __attribute__((address_space(1))) void GPTR;
typedef __attribute__((address_space(3))) void LPTR;

// ---------------- k1b: per-(b,g) best anchor (argmax over axis 0) ----------------
// + fold of all scalar zeroing (runs first in stream; block (0,0) always valid).
__global__ __launch_bounds__(256) void k1b(const float* __restrict__ anchors,
                                           const float* __restrict__ gts,
                                           const int* __restrict__ counts,
                                           int* __restrict__ best_anchor,
                                           int* __restrict__ numpos_b,
                                           float* __restrict__ fsums,
                                           float* __restrict__ neg_sum_b,
                                           int* __restrict__ done) {
    const int b = blockIdx.y, g = blockIdx.x;
    const int t = threadIdx.x;
    if (g == 0 && b == 0) {   // zero accumulators for k2/k3b (poisoned workspace)
        if (t < Bn) { numpos_b[t] = 0; neg_sum_b[t] = 0.f; }
        if (t == Bn) { fsums[0] = 0.f; fsums[1] = 0.f; }
        if (t == Bn + 1) *done = 0;
    }
    const int cnt = counts[b];
    if (g >= cnt) { if (t == 0) best_anchor[b * Gn + g] = 0; return; }  // never applied
    const float bx0 = gts[(b * Gn + g) * 5 + 0], by0 = gts[(b * Gn + g) * 5 + 1];
    const float bx1 = gts[(b * Gn + g) * 5 + 2], by1 = gts[(b * Gn + g) * 5 + 3];
    const float area_b = (bx1 - bx0) * (by1 - by0);
    const float4* a4 = (const float4*)anchors;
    float best = -2.f;
    int bidx = 0x7fffffff;
    for (int base = t; base < An; base += 1024) {
        const int a1 = base + 256, a2 = base + 512, a3 = base + 768;
        const float4 av0 = a4[base];
        float4 av1, av2, av3;
        const bool ok1 = a1 < An, ok2 = a2 < An, ok3 = a3 < An;
        if (ok1) av1 = a4[a1];
        if (ok2) av2 = a4[a2];
        if (ok3) av3 = a4[a3];
        {
            const float area_a = (av0.z - av0.x) * (av0.w - av0.y);
            const float w = fmaxf(fminf(av0.z, bx1) - fmaxf(av0.x, bx0), 0.f);
            const float h = fmaxf(fminf(av0.w, by1) - fmaxf(av0.y, by0), 0.f);
            const float inter = w * h;
            const float iou = inter / (area_a + area_b - inter + 1e-10f);
            if (iou > best) { best = iou; bidx = base; }
        }
        if (ok1) {
            const float area_a = (av1.z - av1.x) * (av1.w - av1.y);
            const float w = fmaxf(fminf(av1.z, bx1) - fmaxf(av1.x, bx0), 0.f);
            const float h = fmaxf(fminf(av1.w, by1) - fmaxf(av1.y, by0), 0.f);
            const float inter = w * h;
            const float iou = inter / (area_a + area_b - inter + 1e-10f);
            if (iou > best) { best = iou; bidx = a1; }
        }
        if (ok2) {
            const float area_a = (av2.z - av2.x) * (av2.w - av2.y);
            const float w = fmaxf(fminf(av2.z, bx1) - fmaxf(av2.x, bx0), 0.f);
            const float h = fmaxf(fminf(av2.w, by1) - fmaxf(av2.y, by0), 0.f);
            const float inter = w * h;
            const float iou = inter / (area_a + area_b - inter + 1e-10f);
            if (iou > best) { best = iou; bidx = a2; }
        }
        if (ok3) {
            const float area_a = (av3.z - av3.x) * (av3.w - av3.y);
            const float w = fmaxf(fminf(av3.z, bx1) - fmaxf(av3.x, bx0), 0.f);
            const float h = fmaxf(fminf(av3.w, by1) - fmaxf(av3.y, by0), 0.f);
            const float inter = w * h;
            const float iou = inter / (area_a + area_b - inter + 1e-10f);
            if (iou > best) { best = iou; bidx = a3; }
        }
    }
    __shared__ float rv[256];
    __shared__ int ri[256];
    rv[t] = best; ri[t] = bidx;
    __syncthreads();
    for (int s = 128; s > 0; s >>= 1) {
        if (t < s) {
            const float fv = rv[t + s]; const int fi = ri[t + s];
            if (fv > rv[t] || (fv == rv[t] && fi < ri[t])) { rv[t] = fv; ri[t] = fi; }
        }
        __syncthreads();
    }
    if (t == 0) best_anchor[b * Gn + g] = ri[0];
}

// ---------------- k2: fused match + LSE + losses + mining value ----------------
// Pipelined double-buffered staging (counted vmcnt, never 0 in-loop) PLUS the
// per-anchor IoU argmax (old k1a) computed inline, 4-lane-split per row, and
// the old k1c scatter applied via an O(1) per-block LDS override map built
// from best_anchor (sequential last-write-wins, matching numpy scatter).
__global__ __launch_bounds__(256) void k2(const float* __restrict__ conf,
                                          const float* __restrict__ pred,
                                          const float* __restrict__ gts,
                                          const int* __restrict__ counts,
                                          const float* __restrict__ anchors,
                                          const int* __restrict__ best_anchor,
                                          int* __restrict__ v_int,
                                          int* __restrict__ numpos_b,
                                          float* __restrict__ fsums) {
    __shared__ __align__(16) float sc[2][ROWS * Cn];   // 2 x 20736 B
    __shared__ float4 sb[2][Gn];     // GT boxes for the <=2 batches this block spans
    __shared__ int    sba[2][Gn];    // best_anchor lists
    __shared__ int    scnt[2];
    __shared__ short  ov_g[BROWS];   // local-row -> forced g (or -1)
    __shared__ float s_ce[4], s_loc[4];
    __shared__ int s_n0[4], s_n1[4];
    const int t = threadIdx.x;
    const size_t rowbase = (size_t)blockIdx.x * BROWS;
    const float* gbase = conf + rowbase * Cn;
    const int bf = (int)(rowbase / An);           // block spans at most bf, bf+1
    const size_t split = (size_t)(bf + 1) * An;

    // ---- preload small tables ----
    ov_g[t] = -1; ov_g[t + 256] = -1;
    if (t < 2) scnt[t] = (bf + t < Bn) ? counts[bf + t] : 0;
    if (t < 2 * Gn) {
        const int bi = t / Gn, g = t - bi * Gn;
        if (bf + bi < Bn) {
            const float* gp = &gts[((size_t)(bf + bi) * Gn + g) * 5];
            sb[bi][g] = make_float4(gp[0], gp[1], gp[2], gp[3]);
            sba[bi][g] = best_anchor[(bf + bi) * Gn + g];
        }
    }
    __syncthreads();
    if (t == 0) {   // apply scatter overrides sequentially: last-write-wins (numpy)
        for (int bi = 0; bi < 2; ++bi) {
            if (bf + bi >= Bn) break;
            const int cnt = scnt[bi];
            for (int g = 0; g < cnt; ++g) {
                const int lr = (int)((size_t)(bf + bi) * An + sba[bi][g] - rowbase);
                if (lr >= 0 && lr < BROWS) ov_g[lr] = (short)g;
            }
        }
    }
    __syncthreads();   // ov_g/sb visible to all; drains preload VMEM too

    // ---- prologue: issue chunk 0 staging ----
    if (t < LD_T) {
#pragma unroll
        for (int k = 0; k < LD_K; ++k) {
            const int c = k * LD_T + t;
            __builtin_amdgcn_global_load_lds((GPTR*)(gbase + c * 4), (LPTR*)(&sc[0][0] + c * 4), 16, 0, 0);
        }
    }

    const int r = t >> 2, h = t & 3;      // 4 lanes per row
    const int j0 = h * 20 + (h != 0);     // h=0:[0,21) h=1:[21,41) h=2:[41,61) h=3:[61,81)
    const int j1 = 21 + h * 20;
    float ce = 0.f, loc = 0.f;
    int n0 = 0, n1 = 0;

    for (int cc = 0; cc < NCH; ++cc) {
        if (cc + 1 < NCH) {
            if (t < LD_T) {
                const float* gp = gbase + (size_t)(cc + 1) * (ROWS * Cn);
                float* lp = &sc[(cc + 1) & 1][0];
#pragma unroll
                for (int k = 0; k < LD_K; ++k) {
                    const int c = k * LD_T + t;
                    __builtin_amdgcn_global_load_lds((GPTR*)(gp + c * 4), (LPTR*)(lp + c * 4), 16, 0, 0);
                }
            }
            asm volatile("s_waitcnt vmcnt(6)" ::: "memory");   // chunk cc landed; cc+1 in flight
        } else {
            asm volatile("s_waitcnt vmcnt(0)" ::: "memory");
        }
        __builtin_amdgcn_sched_barrier(0);
        __builtin_amdgcn_s_barrier();
        asm volatile("" ::: "memory");

        const float* row = &sc[cc & 1][0] + r * Cn;
        float s0 = 0.f, s1 = 0.f;
        for (int j = j0; j + 1 < j1; j += 2) { s0 += __expf(row[j]); s1 += __expf(row[j + 1]); }
        if (((j1 - j0) & 1) != 0) s0 += __expf(row[j1 - 1]);
        float s = s0 + s1;
        s += __shfl_xor(s, 1);
        s += __shfl_xor(s, 2);                 // all 4 lanes hold full row sum
        const float lse = logf(s);

        // ---- inline per-anchor IoU argmax (old k1a), 4-lane-split over g ----
        const int lrow = cc * ROWS + r;
        const size_t gidx = rowbase + lrow;
        const int b = (gidx >= split) ? bf + 1 : bf;
        const int bi2 = b - bf;
        const int a = (int)(gidx - (size_t)b * An);
        const float4 av = ((const float4*)anchors)[a];
        const float area_a = (av.z - av.x) * (av.w - av.y);
        const int cnt = scnt[bi2];
        float bestv = -1.0f;
        int bidx = 0x7fffffff;
        for (int g = h; g < cnt; g += 4) {
            const float4 bb = sb[bi2][g];
            const float w = fmaxf(fminf(av.z, bb.z) - fmaxf(av.x, bb.x), 0.f);
            const float hh = fmaxf(fminf(av.w, bb.w) - fmaxf(av.y, bb.y), 0.f);
            const float inter = w * hh;
            const float area_b = (bb.z - bb.x) * (bb.w - bb.y);
            const float iou = inter / (area_a + area_b - inter + 1e-10f);
            if (iou > bestv) { bestv = iou; bidx = g; }   // strict >: lane-local first-win
        }
        {   // cross-lane combine, first-index wins on ties (np argmax)
            float fv = __shfl_xor(bestv, 1); int fi = __shfl_xor(bidx, 1);
            if (fv > bestv || (fv == bestv && fi < bidx)) { bestv = fv; bidx = fi; }
            fv = __shfl_xor(bestv, 2); fi = __shfl_xor(bidx, 2);
            if (fv > bestv || (fv == bestv && fi < bidx)) { bestv = fv; bidx = fi; }
        }

        if (h == 0) {
            const int og = ov_g[lrow];
            if (og >= 0) { bidx = og; bestv = 2.0f; }   // old k1c scatter
            if (bestv < POS_THRESH_C) {
                v_int[gidx] = __float_as_int(lse - row[0]);   // v = -logp0 >= 0
            } else {
                v_int[gidx] = -1;  // positives excluded from mining
                int lab = (int)gts[((size_t)b * Gn + bidx) * 5 + 4];
                lab = lab < 0 ? 0 : (lab > Cn - 1 ? Cn - 1 : lab);
                ce += lse - row[lab];
                if (b == bf) ++n0; else ++n1;
                const float4 bb = sb[bi2][bidx];
                const float acx = (av.x + av.z) * 0.5f, acy = (av.y + av.w) * 0.5f;
                const float aw = av.z - av.x, ah = av.w - av.y;
                float tt[4];
                tt[0] = ((bb.x + bb.z) * 0.5f - acx) / (aw * 0.1f);
                tt[1] = ((bb.y + bb.w) * 0.5f - acy) / (ah * 0.1f);
                tt[2] = logf((bb.z - bb.x) / aw + 1e-10f) / 0.2f;
                tt[3] = logf((bb.w - bb.y) / ah + 1e-10f) / 0.2f;
                const float4 p = ((const float4*)pred)[gidx];
                const float pk[4] = {p.x, p.y, p.z, p.w};
#pragma unroll
                for (int k = 0; k < 4; ++k) {
                    const float nn = fabsf(pk[k] - tt[k]);
                    loc += (nn < BETA_C) ? 0.5f * nn * nn / BETA_C : nn - 0.5f * BETA_C;
                }
            }
        }
        asm volatile("" ::: "memory");
        __builtin_amdgcn_s_barrier();          // half (cc&1) free for overwrite next iter
    }

    // single block-level reduction after all chunks
#pragma unroll
    for (int off = 32; off > 0; off >>= 1) {
        ce += __shfl_down(ce, off);
        loc += __shfl_down(loc, off);
        n0 += __shfl_down(n0, off);
        n1 += __shfl_down(n1, off);
    }
    if ((t & 63) == 0) {
        const int w = t >> 6;
        s_ce[w] = ce; s_loc[w] = loc; s_n0[w] = n0; s_n1[w] = n1;
    }
    __syncthreads();
    if (t == 0) {
        const float CE = s_ce[0] + s_ce[1] + s_ce[2] + s_ce[3];
        const float LC = s_loc[0] + s_loc[1] + s_loc[2] + s_loc[3];
        const int N0 = s_n0[0] + s_n0[1] + s_n0[2] + s_n0[3];
        const int N1 = s_n1[0] + s_n1[1] + s_n1[2] + s_n1[3];
        if (CE != 0.f) atomicAdd(&fsums[0], CE);
        if (LC != 0.f) atomicAdd(&fsums[1], LC);
        if (N0 > 0) atomicAdd(&numpos_b[bf], N0);
        if (N1 > 0) atomicAdd(&numpos_b[bf + 1], N1);   // N1>0 implies bf+1 <= 15
    }
}

// ---------------- k3b: histogram + threshold + exact top-K + final combine ----
// Pass 1 builds the per-batch histogram in LDS (old k3a, v_int L2/LLC-hot from
// k2); pass 2 selects + sums. Final combine (old k4) by the last-done block,
// with deterministic b=0..15 summation order (matches previous k4 exactly).
__global__ __launch_bounds__(256) void k3b(const int* __restrict__ v_int,
                                           const int* __restrict__ numpos_b,
                                           const float* __restrict__ fsums,
                                           float* __restrict__ neg_sum_b,
                                           int* __restrict__ done,
                                           float* __restrict__ out) {
    const int b = blockIdx.x, t = threadIdx.x;
    const int npb = numpos_b[b];
    const long long K = 3LL * npb;
    const int n_nonpos = An - npb;
    __shared__ int h[NBUCK];
    __shared__ int gsfx[256];
    __shared__ int s_kt, s_r, s_m;
    __shared__ float fred[256];
    __shared__ float list[LISTCAP];
    const int4* v4 = (const int4*)(v_int + (size_t)b * An);
    const int N4 = An / 4;
    const bool selAll = (K >= n_nonpos);
    float blocksum = 0.f;
    if (K > 0) {
        int kt = -1, r = 0;
        if (!selAll) {
            // ---- pass 1: histogram ----
            for (int i = t; i < NBUCK; i += 256) h[i] = 0;
            if (t == 0) s_m = 0;
            __syncthreads();
            for (int i = t; i < N4; i += 256) {
                const int4 x4 = v4[i];
                const int xs[4] = {x4.x, x4.y, x4.z, x4.w};
#pragma unroll
                for (int q = 0; q < 4; ++q) {
                    const int x = xs[q];
                    if (x < 0) continue;
                    int bin = (int)(__int_as_float(x) * 64.0f);
                    bin = bin > NBUCK - 1 ? NBUCK - 1 : bin;
                    atomicAdd(&h[bin], 1);
                }
            }
            __syncthreads();
            // ---- threshold selection ----
            gsfx[t] = h[4 * t] + h[4 * t + 1] + h[4 * t + 2] + h[4 * t + 3];
            __syncthreads();
            if (t == 0) {  // suffix over 256 groups: gsfx[i] := count in groups > i
                int acc = 0;
                for (int i = 255; i >= 0; --i) { const int tmp = gsfx[i]; gsfx[i] = acc; acc += tmp; }
            }
            __syncthreads();
            {
                const int base = 4 * t;
                int cg[4];
                cg[3] = gsfx[t];
                cg[2] = cg[3] + h[base + 3];
                cg[1] = cg[2] + h[base + 2];
                cg[0] = cg[1] + h[base + 1];
#pragma unroll
                for (int q = 0; q < 4; ++q) {
                    if (cg[q] < K && K <= cg[q] + (long long)h[base + q]) {
                        s_kt = base + q; s_r = (int)(K - cg[q]);
                    }
                }
            }
            __syncthreads();
            kt = s_kt; r = s_r;
        } else {
            if (t == 0) s_m = 0;
            __syncthreads();
        }
        // ---- pass 2: select + sum ----
        float s = 0.f;
        for (int i = t; i < N4; i += 256) {
            const int4 x4 = v4[i];
            const int xs[4] = {x4.x, x4.y, x4.z, x4.w};
#pragma unroll
            for (int q = 0; q < 4; ++q) {
                const int x = xs[q];
                if (x < 0) continue;
                const float v = __int_as_float(x);
                if (selAll) { s += v; continue; }
                int bin = (int)(v * 64.0f);
                bin = bin > NBUCK - 1 ? NBUCK - 1 : bin;
                if (bin > kt) s += v;
                else if (bin == kt) {
                    const int p = atomicAdd(&s_m, 1);
                    if (p < LISTCAP) list[p] = v;
                }
            }
        }
        __syncthreads();
        if (!selAll) {
            int M = s_m; M = M > LISTCAP ? LISTCAP : M;
            // exact tie-aware top-r: take x_i iff (#greater) + (#equal, smaller idx) < r
            for (int i = t; i < M; i += 256) {
                const float x = list[i];
                int cnt = 0;
                for (int j = 0; j < M; ++j) {
                    const float y = list[j];
                    cnt += (y > x) || (y == x && j < i);
                }
                if (cnt < r) s += x;
            }
        }
        fred[t] = s;
        __syncthreads();
        for (int st = 128; st > 0; st >>= 1) {
            if (t < st) fred[t] += fred[t + st];
            __syncthreads();
        }
        blocksum = fred[0];
    }
    // ---- publish + last-block combine (old k4) ----
    if (t == 0) {
        atomicExch(&neg_sum_b[b], blocksum);   // device-scope visible store
        __threadfence();
        const int old = atomicAdd(done, 1);
        if (old == Bn - 1) {
            float neg = 0.f;
            for (int bb = 0; bb < Bn; ++bb)
                neg += atomicAdd(&neg_sum_b[bb], 0.0f);   // coherence-point reads, fixed order
            int np = 0;
            for (int bb = 0; bb < Bn; ++bb) np += numpos_b[bb];
            const float num_pos = fmaxf(1.f, (float)np);
            const float denom = num_pos * 4.f;
            out[0] = fsums[1] / denom;           // localisation loss
            out[1] = (fsums[0] + neg) / denom;   // classification loss
        }
    }
}

extern "C" void kernel_launch(void* const* d_in, const int* in_sizes, int n_in,
                              void* d_out, int out_size, void* d_ws, size_t ws_size,
                              hipStream_t stream) {
    const float* conf    = (const float*)d_in[0];
    const float* pred    = (const float*)d_in[1];
    const float* gts     = (const float*)d_in[2];
    const int*   counts  = (const int*)d_in[3];
    const float* anchors = (const float*)d_in[4];
    float* out = (float*)d_out;

    const size_t BA = (size_t)Bn * An;
    char* w = (char*)d_ws;
    int*   v_int       = (int*)w;   w += BA * sizeof(int);
    int*   best_anchor = (int*)w;   w += Bn * Gn * sizeof(int);
    int*   numpos_b    = (int*)w;   w += 64;
    float* fsums       = (float*)w; w += 64;   // [0]=ce_pos_sum [1]=loc_sum
    float* neg_sum_b   = (float*)w; w += 64;
    int*   done        = (int*)w;   w += 64;

    hipLaunchKernelGGL(k1b, dim3(Gn, Bn), dim3(256), 0, stream,
                       anchors, gts, counts, best_anchor,
                       numpos_b, fsums, neg_sum_b, done);
    hipLaunchKernelGGL(k2, dim3((unsigned)(BA / BROWS)), dim3(256), 0, stream,
                       conf, pred, gts, counts, anchors, best_anchor,
                       v_int, numpos_b, fsums);
    hipLaunchKernelGGL(k3b, dim3(Bn), dim3(256), 0, stream,
                       v_int, numpos_b, fsums, neg_sum_b, done, out);
}